// Round 14
// baseline (96.152 us; speedup 1.0000x reference)
//
#include <hip/hip_runtime.h>
#include <cstdint>

// B=16384 rows, K=2048 centers, D=128, T=1.0
// Outputs (flat, f32): out[B*D], center[K*D], label[B]
#define NB 16384
#define NK 2048
#define ND 128
#define MARGIN 0.10f
#define CAP 2048
#define XPITCH 132   // padded LDS x-row stride (floats): breaks bank aliasing

typedef __attribute__((ext_vector_type(8))) short bf16x8;
typedef __attribute__((ext_vector_type(4))) float f32x4;
typedef unsigned long long u64;

__device__ __forceinline__ unsigned short f2bf(float f) {
    unsigned u = __float_as_uint(f);
    u += 0x7fffu + ((u >> 16) & 1u);          // round-to-nearest-even
    return (unsigned short)(u >> 16);
}

// order-preserving uint encoding for float atomicMin (handles negatives)
__device__ __forceinline__ unsigned fkey(float f) {
    unsigned u = __float_as_uint(f);
    return u ^ ((unsigned)((int)u >> 31) | 0x80000000u);
}
__device__ __forceinline__ float funkey(unsigned k) {
    unsigned u = (k & 0x80000000u) ? (k ^ 0x80000000u) : ~k;
    return __uint_as_float(u);
}

// ---------------------------------------------------------------------------
// Prep (136 blocks):
//  [0,128)    cbf: center -> bf16 MFMA B-frag layout
//  [128,136)  c2 (chain identical to R1)
// ---------------------------------------------------------------------------
__global__ __launch_bounds__(256)
void prep(const float* __restrict__ c,
          unsigned short* __restrict__ cbf,
          float* __restrict__ c2) {
    const int bid = blockIdx.x;
    const int tid = threadIdx.x;
    if (bid < 128) {
        int t = bid * 256 + tid;              // 0..32767
        int lane = t & 63, s = (t >> 6) & 3, kt = t >> 8;
        int kc = kt * 16 + (lane & 15);
        int d0 = s * 32 + (lane >> 4) * 8;
        const float* src = c + (long)kc * ND + d0;
        unsigned short h[8];
#pragma unroll
        for (int j = 0; j < 8; ++j) h[j] = f2bf(src[j]);
        int4 pk;
        pk.x = h[0] | (h[1] << 16); pk.y = h[2] | (h[3] << 16);
        pk.z = h[4] | (h[5] << 16); pk.w = h[6] | (h[7] << 16);
        ((int4*)cbf)[t] = pk;
    } else {
        int k = (bid - 128) * 256 + tid;      // 0..2047
        const float4* row = (const float4*)(c + (long)k * ND);
        float s = 0.f;
#pragma unroll 8
        for (int i = 0; i < ND / 4; ++i) {
            float4 v = row[i];
            s += v.x * v.x + v.y * v.y + v.z * v.z + v.w * v.w;
        }
        c2[k] = s;
    }
}

// ---------------------------------------------------------------------------
// Main: 512 blocks x 512 threads (8 waves). Block owns 32 rows x ALL 2048 k.
// Two MFMA sweeps + exact fp32 refine (R1-identical chain); direct outputs;
// folds the center->out_center copy (overlaps with compute).
//
// ISSUE-BOUND MODEL (R13 analysis): MfmaUtil is FLOP-fraction (R9: 8.6GF/43us
// = 8% == counter), NOT pipe time. Re-costed: MFMA issue ~310 + VALU ~280 of
// ~700 cyc/round -> SIMD ~84% issue-busy. Explains: more waves hurt (R10),
// fewer bytes neutral (R5/R9/R11/R12), ILP neutral (R4). Only lever: fewer
// issued ops.
//
// R14 trims (structure unchanged):
//  - shifted-space epilogue: track s = d2 - x2row = fmaf(-2,acc,c2v); kills
//    8 v_add/iter in sweep 1 and 8 in sweep 2 (thresholds pre-shifted).
//    s may be negative -> order-preserving uint key for bmin atomicMin.
//  - no prefetch rotation (R4: neutral; saves 16 v_mov/iter), unroll 2.
//  Window semantics identical modulo ~1ulp (MARGIN=0.1 >> that); refine
//  chain untouched -> labels exact.
// ---------------------------------------------------------------------------
__global__ __launch_bounds__(512, 4)
void kmeans_main(const float* __restrict__ x,
                 const float* __restrict__ center,
                 const unsigned short* __restrict__ cbf,
                 const float* __restrict__ c2,
                 float* __restrict__ out,
                 float* __restrict__ out_center,
                 float* __restrict__ label_out) {
    __shared__ float xs[32 * XPITCH];         // 16.9 KB fp32 x rows
    __shared__ float c2s[NK];                 // 8 KB center norms
    __shared__ float x2s[32];
    __shared__ unsigned bmin[32];             // fkey-encoded shifted min
    __shared__ u64 best[32];
    __shared__ unsigned buf[CAP];             // 8 KB candidate list
    __shared__ unsigned cnt;

    const int tid  = threadIdx.x;
    const int lane = tid & 63;
    const int wave = __builtin_amdgcn_readfirstlane(tid >> 6);  // 0..7
    const long rb  = (long)blockIdx.x * 32;

    // ---- stage x rows -> LDS (coalesced, 2 float4/thread) ----
    {
        int idx = tid;                        // float4 index 0..1023
        int r = idx >> 5, q = idx & 31;
        ((float4*)(xs + r * XPITCH))[q] = ((const float4*)(x + (rb + r) * ND))[q];
        idx = tid + 512;
        r = idx >> 5; q = idx & 31;
        ((float4*)(xs + r * XPITCH))[q] = ((const float4*)(x + (rb + r) * ND))[q];
    }
    // ---- stage c2 -> LDS (4 floats/thread, coalesced) ----
    ((float4*)c2s)[tid] = ((const float4*)c2)[tid];
    // ---- folded prep-copy: this block's slice of center -> out_center ----
    if (tid < 128) {
        long ci = (long)blockIdx.x * 128 + tid;     // 512*128 = 64K float4 total
        ((float4*)out_center)[ci] = ((const float4*)center)[ci];
    }
    if (tid < 32) { bmin[tid] = 0xffffffffu; best[tid] = ~0ULL; }
    if (tid == 0) cnt = 0;
    __syncthreads();

    // ---- x2 per row: chain IDENTICAL to R1 (float2, 6-level butterfly) ----
    for (int i = 0; i < 4; ++i) {
        int r = wave * 4 + i;
        float2 v = *(const float2*)(xs + r * XPITCH + lane * 2);
        float s = v.x * v.x + v.y * v.y;
#pragma unroll
        for (int off = 32; off; off >>= 1) s += __shfl_xor(s, off, 64);
        if (lane == 0) x2s[r] = s;
    }
    __syncthreads();

    // ---- A-frags into registers (reused by both sweeps) ----
    bf16x8 af[2][4];
#pragma unroll
    for (int rt = 0; rt < 2; ++rt)
#pragma unroll
        for (int s = 0; s < 4; ++s) {
            const float* p = xs + (rt * 16 + (lane & 15)) * XPITCH
                               + s * 32 + (lane >> 4) * 8;
            float4 u0 = ((const float4*)p)[0];
            float4 u1 = ((const float4*)p)[1];
            bf16x8 a;
            a[0] = (short)f2bf(u0.x); a[1] = (short)f2bf(u0.y);
            a[2] = (short)f2bf(u0.z); a[3] = (short)f2bf(u0.w);
            a[4] = (short)f2bf(u1.x); a[5] = (short)f2bf(u1.y);
            a[6] = (short)f2bf(u1.z); a[7] = (short)f2bf(u1.w);
            af[rt][s] = a;
        }

    const bf16x8* CF = (const bf16x8*)cbf;
    const int kbase = wave * 256;
    const int kt0   = kbase >> 4;

    // ---- sweep 1: shifted-space min over this wave's 256 k ----
    // s = d2 - x2row = c2 - 2*dot : x2 add deleted from the loop
    float smin[2][4];
#pragma unroll
    for (int rt = 0; rt < 2; ++rt)
#pragma unroll
        for (int reg = 0; reg < 4; ++reg) smin[rt][reg] = __builtin_inff();

#pragma unroll 2
    for (int ct = 0; ct < 16; ++ct) {
        const int kt = kt0 + ct;
        bf16x8 bfr[4];
#pragma unroll
        for (int s = 0; s < 4; ++s) bfr[s] = CF[(kt * 4 + s) * 64 + lane];
        f32x4 acc0 = {0.f,0.f,0.f,0.f}, acc1 = {0.f,0.f,0.f,0.f};
#pragma unroll
        for (int s = 0; s < 4; ++s) {
            acc0 = __builtin_amdgcn_mfma_f32_16x16x32_bf16(af[0][s], bfr[s], acc0, 0,0,0);
            acc1 = __builtin_amdgcn_mfma_f32_16x16x32_bf16(af[1][s], bfr[s], acc1, 0,0,0);
        }
        float c2v = c2s[kt * 16 + (lane & 15)];
#pragma unroll
        for (int reg = 0; reg < 4; ++reg) {
            smin[0][reg] = fminf(smin[0][reg], fmaf(-2.f, acc0[reg], c2v));
            smin[1][reg] = fminf(smin[1][reg], fmaf(-2.f, acc1[reg], c2v));
        }
    }

    // cross-lane min over the 16 cols (lane&15 group), then block combine
#pragma unroll
    for (int rt = 0; rt < 2; ++rt)
#pragma unroll
        for (int reg = 0; reg < 4; ++reg) {
            float v = smin[rt][reg];
#pragma unroll
            for (int off = 1; off < 16; off <<= 1)
                v = fminf(v, __shfl_xor(v, off, 64));
            if ((lane & 15) == 0)             // shifted value may be <0 -> fkey
                atomicMin(&bmin[rt * 16 + (lane >> 4) * 4 + reg], fkey(v));
        }
    __syncthreads();

    // shifted thresholds: compare s <= s_min + MARGIN (same shift both sides)
    float thr[2][4];
#pragma unroll
    for (int rt = 0; rt < 2; ++rt)
#pragma unroll
        for (int reg = 0; reg < 4; ++reg)
            thr[rt][reg] = funkey(bmin[rt * 16 + (lane >> 4) * 4 + reg]) + MARGIN;

    // ---- sweep 2: recompute, filter candidates within MARGIN of block min ----
#pragma unroll 2
    for (int ct = 0; ct < 16; ++ct) {
        const int kt = kt0 + ct;
        bf16x8 bfr[4];
#pragma unroll
        for (int s = 0; s < 4; ++s) bfr[s] = CF[(kt * 4 + s) * 64 + lane];
        f32x4 acc0 = {0.f,0.f,0.f,0.f}, acc1 = {0.f,0.f,0.f,0.f};
#pragma unroll
        for (int s = 0; s < 4; ++s) {
            acc0 = __builtin_amdgcn_mfma_f32_16x16x32_bf16(af[0][s], bfr[s], acc0, 0,0,0);
            acc1 = __builtin_amdgcn_mfma_f32_16x16x32_bf16(af[1][s], bfr[s], acc1, 0,0,0);
        }
        float c2v = c2s[kt * 16 + (lane & 15)];
        const int col = kt * 16 + (lane & 15);
#pragma unroll
        for (int reg = 0; reg < 4; ++reg) {
            float s0 = fmaf(-2.f, acc0[reg], c2v);
            if (s0 <= thr[0][reg]) {
                unsigned rloc = (lane >> 4) * 4 + reg;          // rt=0
                unsigned idx = atomicAdd(&cnt, 1u);
                if (idx < CAP) buf[idx] = (rloc << 11) | (unsigned)col;
            }
            float s1 = fmaf(-2.f, acc1[reg], c2v);
            if (s1 <= thr[1][reg]) {
                unsigned rloc = 16 + (lane >> 4) * 4 + reg;     // rt=1
                unsigned idx = atomicAdd(&cnt, 1u);
                if (idx < CAP) buf[idx] = (rloc << 11) | (unsigned)col;
            }
        }
    }
    __syncthreads();

    // ---- exact refine: fp32 chain IDENTICAL to R1 (serial fmaf dot,
    //      t=x2+c2, fmaf(-2,dot,t), max, sqrt; u64 key -> lowest k on tie) ----
    unsigned n = cnt; if (n > CAP) n = CAP;
    for (unsigned i = tid; i < n; i += 512) {
        unsigned pc = buf[i];
        int rloc = pc >> 11, col = pc & (NK - 1);
        const float* xr = xs + rloc * XPITCH;
        const float* cr = center + (long)col * ND;
        float dot = 0.f;
#pragma unroll 8
        for (int d = 0; d < ND; ++d) dot = fmaf(xr[d], cr[d], dot);
        float t = x2s[rloc] + c2s[col];
        float f = fmaxf(fmaf(-2.0f, dot, t), 0.0f);
        float s = __builtin_sqrtf(f);
        u64 key = ((u64)__float_as_uint(s) << 32) | (unsigned)col;
        atomicMin(&best[rloc], key);
    }
    __syncthreads();

    // ---- direct output: gather center[bk] per row + label ----
    for (int i = 0; i < 4; ++i) {
        int rloc = wave * 4 + i;
        int bk = (int)(best[rloc] & 0xffffffffULL);
        float2 cv = ((const float2*)(center + (long)bk * ND))[lane];
        ((float2*)(out + (rb + rloc) * ND))[lane] = cv;
        if (lane == 0) label_out[rb + rloc] = (float)bk;
    }
}

// ---------------------------------------------------------------------------
extern "C" void kernel_launch(void* const* d_in, const int* in_sizes, int n_in,
                              void* d_out, int out_size, void* d_ws, size_t ws_size,
                              hipStream_t stream) {
    const float* x      = (const float*)d_in[0];   // [B][D]
    const float* center = (const float*)d_in[1];   // [K][D]
    float* out = (float*)d_out;

    float* out_x      = out;                        // [B*D]
    float* out_center = out + (long)NB * ND;        // [K*D]
    float* out_label  = out_center + (long)NK * ND; // [B]

    // Workspace: cbf[K*D]u16 (0.5MB), c2[K]f32
    unsigned short* cbf = (unsigned short*)d_ws;
    float* c2 = (float*)(cbf + (size_t)NK * ND);

    prep<<<136, 256, 0, stream>>>(center, cbf, c2);
    kmeans_main<<<NB / 32, 512, 0, stream>>>(x, center, cbf, c2,
                                             out_x, out_center, out_label);
}